// Round 9
// baseline (270.883 us; speedup 1.0000x reference)
//
#include <hip/hip_runtime.h>

#define K_ITER   30
#define MU       0.01f
#define EPS      1e-6f
#define MAX_LS   25
#define FULLMASK 0x01FFFFFFu
#define MM       128
#define NN       256
#define NPROB    512
#define NTHR     512          // 8 waves/block; launch_bounds(512,4) -> 2 blocks/CU guaranteed

// ---- ws layout (unsigned words); zero-initialized each launch ----
// flag[p]  : one 128B line per block: ((k+1)<<25) | bad-bits   (written by block p)
// bcast[i] : 16 lines: ((k+1)<<25) | gm                        (written by master t0)
#define LSTRIDE 32
#define NBC     16
#define W_FLAG(p)  ((p)*LSTRIDE)
#define W_BCAST(i) (NPROB*LSTRIDE + (i)*LSTRIDE)
#define W_END      (NPROB*LSTRIDE + NBC*LSTRIDE)   // 16896 words

// --- cross-lane helpers ---------------------------------------------------
#define RED64_AND(v) do { v &= __shfl_xor(v, 1);  v &= __shfl_xor(v, 2);  v &= __shfl_xor(v, 4); \
                          v &= __shfl_xor(v, 8);  v &= __shfl_xor(v, 16); v &= __shfl_xor(v, 32); } while (0)
#define RED64_OR(v)  do { v |= __shfl_xor(v, 1);  v |= __shfl_xor(v, 2);  v |= __shfl_xor(v, 4); \
                          v |= __shfl_xor(v, 8);  v |= __shfl_xor(v, 16); v |= __shfl_xor(v, 32); } while (0)
#define RED64_MIN(v) do { v = fminf(v, __shfl_xor(v, 1));  v = fminf(v, __shfl_xor(v, 2)); \
                          v = fminf(v, __shfl_xor(v, 4));  v = fminf(v, __shfl_xor(v, 8)); \
                          v = fminf(v, __shfl_xor(v, 16)); v = fminf(v, __shfl_xor(v, 32)); } while (0)

#define AGLOAD(p)     __hip_atomic_load((p),      __ATOMIC_RELAXED, __HIP_MEMORY_SCOPE_AGENT)
#define AGSTORE(p, v) __hip_atomic_store((p), (v), __ATOMIC_RELAXED, __HIP_MEMORY_SCOPE_AGENT)

// DPP circular row_ror reduction: sum over each 16-lane group; every lane of
// the group ends with the full 16-sum (VALU pipe only — no DS traffic).
__device__ __forceinline__ float red16_add(float v) {
    v += __int_as_float(__builtin_amdgcn_update_dpp(0, __float_as_int(v), 0x128, 0xF, 0xF, false)); // ror:8
    v += __int_as_float(__builtin_amdgcn_update_dpp(0, __float_as_int(v), 0x124, 0xF, 0xF, false)); // ror:4
    v += __int_as_float(__builtin_amdgcn_update_dpp(0, __float_as_int(v), 0x122, 0xF, 0xF, false)); // ror:2
    v += __int_as_float(__builtin_amdgcn_update_dpp(0, __float_as_int(v), 0x121, 0xF, 0xF, false)); // ror:1
    return v;
}

// -------------------------------------------------------- ws clear ----
__global__ void lbp_ws_init(unsigned* __restrict__ wsu)
{
    const int idx = blockIdx.x * 1024 + threadIdx.x;
    if (idx < W_END) wsu[idx] = 0u;
}

// Persistent kernel: block p owns problem p; A slice lives in 64 regs/thread
// (AGPR half of the unified file; hard budget 128/thread for 2 blocks/CU).
// Lane (g=lane>>4, j=lane&15) of wave w holds rows 16w+4g+r and col chunks
// [4j+64c..+3].  ax/pg row state in LDS; ax recurrence ax -= step*pg.
// Grad phase: wave w owns cols 32w..32w+31; lane&31 -> col (bank-conflict-
// free), lane>>5 -> partial-half; the 25-step line search is split across
// the two halves and merged in the same AND butterfly.
// Per-wave mask slots (s_redN/s_redM) replace LDS atomics.
__global__ __launch_bounds__(NTHR, 4)
void lbp_fused(const float* __restrict__ xraw_g,
               const float* __restrict__ A_g,
               const float* __restrict__ b_g,
               const float* __restrict__ lower_g,
               float* __restrict__ out_g,
               unsigned* __restrict__ wsu)
{
    const int p    = blockIdx.x;
    const int t    = threadIdx.x;
    const int lane = t & 63;
    const int wave = t >> 6;          // 0..7
    const int g    = lane >> 4;       // 0..3  row sub-group
    const int j    = lane & 15;       // 0..15 col sub-group
    const int wb   = wave * 16;       // wave's base row

    const float* A = A_g + (size_t)p * (MM * NN);

    __shared__ __align__(16) float s_x[NN];
    __shared__ __align__(16) float s_grad[NN];
    __shared__ __align__(16) float s_xraw[NN];
    __shared__ __align__(16) float s_lower[NN];
    __shared__ __align__(16) float s_p1g[32][NN];          // per-(wave,g) A^T w partials
    __shared__ float s_ax[MM], s_pg[MM];                   // row state (j==0 writes)
    __shared__ float s_redw[8];
    __shared__ unsigned s_redu[8];
    __shared__ unsigned s_redN[8], s_redM[8];              // per-wave mask slots
    __shared__ float s_step, s_t0;

    // ---- load A slice into registers (only HBM read of A in the solve) ----
    float4 a[4][4];
    {
        const float* base = A + (size_t)(wb + 4 * g) * NN + 4 * j;
        #pragma unroll
        for (int r = 0; r < 4; ++r)
            #pragma unroll
            for (int c = 0; c < 4; ++c)
                a[r][c] = *(const float4*)(base + r * NN + 64 * c);
    }

    if (t < NN) { s_xraw[t] = xraw_g[p * NN + t]; s_lower[t] = lower_g[p * NN + t]; }

    float bbr[4];
    #pragma unroll
    for (int r = 0; r < 4; ++r) bbr[r] = b_g[p * MM + wb + 4 * g + r];

    const float stepj0 = ldexpf(1.0f, -j);   // pass-2 ballot step 2^-j for this lane

    if (t == 0) s_step = 0.0f;
    __syncthreads();

    // ---- init: row stats (ssq, rowsum, A·lower) from registers ----
    float cer[4], clr[4];
    {
        float ssq[4] = {0.f,0.f,0.f,0.f}, rs[4] = {0.f,0.f,0.f,0.f}, al[4] = {0.f,0.f,0.f,0.f};
        #pragma unroll
        for (int c = 0; c < 4; ++c) {
            const float4 lo4 = ((const float4*)s_lower)[j + 16 * c];
            #pragma unroll
            for (int r = 0; r < 4; ++r) {
                const float4 av = a[r][c];
                ssq[r] += av.x*av.x + av.y*av.y + av.z*av.z + av.w*av.w;
                rs[r]  += av.x + av.y + av.z + av.w;
                al[r]  += av.x*lo4.x + av.y*lo4.y + av.z*lo4.z + av.w*lo4.w;
            }
        }
        float alr[4], rsr[4];
        float rmin = INFINITY;
        #pragma unroll
        for (int r = 0; r < 4; ++r) {
            const float ssqs = red16_add(ssq[r]);
            const float rss  = red16_add(rs[r]);
            const float als  = red16_add(al[r]);
            const float rr = fmaxf(sqrtf(ssqs), 1e-12f);
            clr[r] = 1e-12f * rr;                    // slack clamp (unnormalized)
            cer[r] = bbr[r] - EPS * rr;              // feasibility threshold
            const float adw = rss / rr;
            const float sw  = (bbr[r] - als) / rr;
            const float ratio = (adw > 0.f) ? (sw / fmaxf(adw, 1e-12f)) : INFINITY;
            rmin = fminf(rmin, ratio);
            alr[r] = als; rsr[r] = rss;
        }
        RED64_MIN(rmin);
        if (lane == 0) s_redw[wave] = rmin;
        __syncthreads();
        if (t == 0) {
            float m = s_redw[0];
            #pragma unroll
            for (int w = 1; w < 8; ++w) m = fminf(m, s_redw[w]);
            s_t0 = fmaxf(0.5f * m, 2.0f * EPS);
        }
        __syncthreads();
        const float t0v = s_t0;
        float xi = 0.f;
        if (t < NN) { xi = s_lower[t] + t0v; s_x[t] = xi; }
        float axc0[4];
        #pragma unroll
        for (int r = 0; r < 4; ++r) {
            axc0[r] = alr[r] + t0v * rsr[r];
            if (j == 0) { s_ax[wb + 4 * g + r] = axc0[r]; s_pg[wb + 4 * g + r] = 0.f; }
        }

        // feasibility repair (faithful to module; no-op for these inputs)
        int okf = 1;
        #pragma unroll
        for (int r = 0; r < 4; ++r) okf = okf && (axc0[r] <= cer[r]);
        if (t < NN) okf = okf && (xi >= s_lower[t] + EPS);
        const int feas = __syncthreads_and(okf);
        if (!feas) {
            if (t < NN) s_x[t] = 0.5f * (fmaxf(s_x[t], 0.f) + s_lower[t]);
            __syncthreads();
            float axp[4] = {0.f,0.f,0.f,0.f};
            #pragma unroll
            for (int c = 0; c < 4; ++c) {
                const float4 x4 = ((const float4*)s_x)[j + 16 * c];
                #pragma unroll
                for (int r = 0; r < 4; ++r) {
                    const float4 av = a[r][c];
                    axp[r] += av.x*x4.x + av.y*x4.y + av.z*x4.z + av.w*x4.w;
                }
            }
            #pragma unroll
            for (int r = 0; r < 4; ++r) {
                const float s = red16_add(axp[r]);
                if (j == 0) s_ax[wb + 4 * g + r] = s;     // s_pg stays 0
            }
            __syncthreads();
        }
    }

    // ------------------------------ main loop ------------------------------
    for (int k = 0; k < K_ITER; ++k) {
        // pass 1: ax recurrence + barrier weights + gbar partials.
        float axm[4];                         // live through pass 2's ballots
        {
            const float stp = s_step;
            float wm[4];
            #pragma unroll
            for (int r = 0; r < 4; ++r) {
                const int m = wb + 4 * g + r;
                axm[r] = s_ax[m] - stp * s_pg[m];
                wm[r]  = MU / fmaxf(bbr[r] - axm[r], clr[r]);
            }
            if (j == 0) {
                #pragma unroll
                for (int r = 0; r < 4; ++r) s_ax[wb + 4 * g + r] = axm[r];
            }
            #pragma unroll
            for (int c = 0; c < 4; ++c) {
                float4 gb;
                gb.x = a[0][c].x*wm[0] + a[1][c].x*wm[1] + a[2][c].x*wm[2] + a[3][c].x*wm[3];
                gb.y = a[0][c].y*wm[0] + a[1][c].y*wm[1] + a[2][c].y*wm[2] + a[3][c].y*wm[3];
                gb.z = a[0][c].z*wm[0] + a[1][c].z*wm[1] + a[2][c].z*wm[2] + a[3][c].z*wm[3];
                gb.w = a[0][c].w*wm[0] + a[1][c].w*wm[1] + a[2][c].w*wm[2] + a[3][c].w*wm[3];
                ((float4*)s_p1g[wave * 4 + g])[j + 16 * c] = gb;
            }
        }
        __syncthreads();                                   // sync1

        // grad + n-side line-search — wave w owns cols 32w..32w+31.
        // lane&31 -> col (bank = lane&31: conflict-free), lane>>5 -> half.
        // half 0 sums partial rows 0..15 & tests steps l=0..12;
        // half 1 sums rows 16..31 & tests l=13..24 (st0 = 2^-13 exact).
        {
            const int col  = (wave << 5) | (lane & 31);
            const int half = lane >> 5;
            float gsum = 0.f;
            #pragma unroll
            for (int q = 0; q < 16; ++q) gsum += s_p1g[half * 16 + q][col];
            gsum += __shfl_xor(gsum, 32);
            const float xt = s_x[col];
            const float gr = (xt - s_xraw[col]) + gsum + MU / fmaxf(xt - s_lower[col], 1e-12f);
            if (half == 0) s_grad[col] = gr;
            unsigned mn = 0u;
            const float loe = s_lower[col] + EPS;
            float st = half ? 0x1p-13f : 1.0f;
            #pragma unroll
            for (int i = 0; i < 13; ++i) {                 // half1's i=12 -> bit 25 (stripped)
                if (xt - st * gr >= loe) mn |= (1u << (half * 13 + i));
                st *= 0.5f;
            }
            mn |= half ? ~0x03FFE000u : ~0x00001FFFu;      // own-range only
            RED64_AND(mn);                                 // xor32 merges halves
            if (lane == 0) s_redN[wave] = mn;
        }
        __syncthreads();                                   // sync2

        // pass 2: pg = A*grad + fused m-side line-search ballots (vs axm)
        {
            float pg[4] = {0.f,0.f,0.f,0.f};
            #pragma unroll
            for (int c = 0; c < 4; ++c) {
                const float4 g4 = ((const float4*)s_grad)[j + 16 * c];
                #pragma unroll
                for (int r = 0; r < 4; ++r) {
                    const float4 av = a[r][c];
                    pg[r] += av.x*g4.x + av.y*g4.y + av.z*g4.z + av.w*g4.w;
                }
            }
            unsigned mand = 0xFFFFFFFFu;
            #pragma unroll
            for (int r = 0; r < 4; ++r) {
                const float pgs = red16_add(pg[r]);        // all 16 lanes get row sum
                if (j == 0) s_pg[wb + 4 * g + r] = pgs;
                const bool ok0 = (axm[r] - stepj0 * pgs) <= cer[r];              // step j
                const bool ok1 = (axm[r] - (stepj0 * 0x1p-16f) * pgs) <= cer[r]; // step j+16
                const unsigned long long b0 = __ballot(ok0);
                const unsigned long long b1 = __ballot(ok1);
                const unsigned f = ((unsigned)(b0 >> (16 * g)) & 0xFFFFu)
                                 | (((unsigned)(b1 >> (16 * g)) & 0x1FFu) << 16);
                mand &= (f | 0xFE000000u);
            }
            mand &= __shfl_xor(mand, 16);
            mand &= __shfl_xor(mand, 32);
            if (lane == 0) s_redM[wave] = mand;
        }
        __syncthreads();                                   // sync3 (mask slots final)

        // ---- grid consensus: flag-store + master OR-reduce + broadcast ----
        const unsigned tag = (unsigned)(k + 1) << 25;
        if (p == 0) {
            __builtin_amdgcn_s_setprio(1);                 // master reduce is grid-critical
            unsigned bad;
            if (t == 0) {
                unsigned loc = 0xFFFFFFFFu;
                #pragma unroll
                for (int w = 0; w < 8; ++w) loc &= s_redN[w] & s_redM[w];
                bad = (~loc) & FULLMASK;
            } else {
                unsigned v;
                while ((((v = AGLOAD(&wsu[W_FLAG(t)])) >> 25)) != (unsigned)(k + 1))
                    __builtin_amdgcn_s_sleep(1);
                bad = v & FULLMASK;
            }
            RED64_OR(bad);
            if (lane == 0) s_redu[wave] = bad;
            __syncthreads();
            if (t == 0) {
                unsigned orall = 0u;
                #pragma unroll
                for (int w = 0; w < 8; ++w) orall |= s_redu[w];
                const unsigned gm = FULLMASK & ~orall;
                #pragma unroll
                for (int i = 0; i < NBC; ++i)              // bcast ASAP, before sync
                    AGSTORE(&wsu[W_BCAST(i)], tag | gm);
                s_step = gm ? ldexpf(1.0f, -(__ffs(gm) - 1)) : 0.0f;
            }
            __builtin_amdgcn_s_setprio(0);
            __syncthreads();                               // sync4 (master)
        } else {
            if (t == 0) {
                unsigned loc = 0xFFFFFFFFu;
                #pragma unroll
                for (int w = 0; w < 8; ++w) loc &= s_redN[w] & s_redM[w];
                AGSTORE(&wsu[W_FLAG(p)], tag | ((~loc) & FULLMASK));
                unsigned v;
                while ((((v = AGLOAD(&wsu[W_BCAST(p & (NBC - 1))])) >> 25)) != (unsigned)(k + 1))
                    __builtin_amdgcn_s_sleep(1);
                const unsigned gm = v & FULLMASK;
                s_step = gm ? ldexpf(1.0f, -(__ffs(gm) - 1)) : 0.0f;
            }
            __syncthreads();                               // sync4
        }

        // epilogue: x update only (ax advanced by next pass 1's recurrence)
        if (t < NN) s_x[t] -= s_step * s_grad[t];
        // ordering: s_x writes -> next sync1 -> grad reads; s_ax/s_pg writes
        // (pass1/pass2, before sync3) -> next pass1 reads (after sync4);
        // s_step written before sync4, consumed here and at next pass1 top.
    }

    if (t < NN) out_g[p * NN + t] = fmaxf(s_x[t], 0.0f);
}

// -------------------------------------------------------------- launch ----
extern "C" void kernel_launch(void* const* d_in, const int* in_sizes, int n_in,
                              void* d_out, int out_size, void* d_ws, size_t ws_size,
                              hipStream_t stream) {
    const float* xraw  = (const float*)d_in[0];
    const float* A     = (const float*)d_in[1];
    const float* b     = (const float*)d_in[2];
    const float* lower = (const float*)d_in[3];
    float* out = (float*)d_out;
    unsigned* wsu = (unsigned*)d_ws;

    lbp_ws_init<<<(W_END + 1023) / 1024, 1024, 0, stream>>>(wsu);
    lbp_fused<<<NPROB, NTHR, 0, stream>>>(xraw, A, b, lower, out, wsu);
}

// Round 10
// 251.716 us; speedup vs baseline: 1.0761x; 1.0761x over previous
//
#include <hip/hip_runtime.h>

#define K_ITER   30
#define MU       0.01f
#define EPS      1e-6f
#define MAX_LS   25
#define FULLMASK 0x01FFFFFFu
#define MM       128
#define NN       256
#define NPROB    512
#define NTHR     512          // 8 waves/block; launch_bounds(512,4) -> 2 blocks/CU guaranteed

// ---- ws layout (unsigned words); zero-initialized each launch ----
// flag[p]  : one 128B line per block: ((k+1)<<25) | bad-bits   (written by block p)
// bcast[i] : 16 lines: ((k+1)<<25) | gm                        (written by master t0)
#define LSTRIDE 32
#define NBC     16
#define W_FLAG(p)  ((p)*LSTRIDE)
#define W_BCAST(i) (NPROB*LSTRIDE + (i)*LSTRIDE)
#define W_END      (NPROB*LSTRIDE + NBC*LSTRIDE)   // 16896 words

// --- cross-lane helpers ---------------------------------------------------
#define RED64_AND(v) do { v &= __shfl_xor(v, 1);  v &= __shfl_xor(v, 2);  v &= __shfl_xor(v, 4); \
                          v &= __shfl_xor(v, 8);  v &= __shfl_xor(v, 16); v &= __shfl_xor(v, 32); } while (0)
#define RED64_OR(v)  do { v |= __shfl_xor(v, 1);  v |= __shfl_xor(v, 2);  v |= __shfl_xor(v, 4); \
                          v |= __shfl_xor(v, 8);  v |= __shfl_xor(v, 16); v |= __shfl_xor(v, 32); } while (0)
#define RED64_MIN(v) do { v = fminf(v, __shfl_xor(v, 1));  v = fminf(v, __shfl_xor(v, 2)); \
                          v = fminf(v, __shfl_xor(v, 4));  v = fminf(v, __shfl_xor(v, 8)); \
                          v = fminf(v, __shfl_xor(v, 16)); v = fminf(v, __shfl_xor(v, 32)); } while (0)

#define AGLOAD(p)     __hip_atomic_load((p),      __ATOMIC_RELAXED, __HIP_MEMORY_SCOPE_AGENT)
#define AGSTORE(p, v) __hip_atomic_store((p), (v), __ATOMIC_RELAXED, __HIP_MEMORY_SCOPE_AGENT)

// DPP circular row_ror reduction: sum over each 16-lane group; every lane of
// the group ends with the full 16-sum (VALU pipe only — no DS traffic).
__device__ __forceinline__ float red16_add(float v) {
    v += __int_as_float(__builtin_amdgcn_update_dpp(0, __float_as_int(v), 0x128, 0xF, 0xF, false)); // ror:8
    v += __int_as_float(__builtin_amdgcn_update_dpp(0, __float_as_int(v), 0x124, 0xF, 0xF, false)); // ror:4
    v += __int_as_float(__builtin_amdgcn_update_dpp(0, __float_as_int(v), 0x122, 0xF, 0xF, false)); // ror:2
    v += __int_as_float(__builtin_amdgcn_update_dpp(0, __float_as_int(v), 0x121, 0xF, 0xF, false)); // ror:1
    return v;
}

// -------------------------------------------------------- ws clear ----
__global__ void lbp_ws_init(unsigned* __restrict__ wsu)
{
    const int idx = blockIdx.x * 1024 + threadIdx.x;
    if (idx < W_END) wsu[idx] = 0u;
}

// Persistent kernel (R8 structure): block p owns problem p; A slice in 64
// regs/thread (AGPR half of unified file; 128-reg budget for 2 blocks/CU).
// Lane (g=lane>>4, j=lane&15) of wave w holds rows 16w+4g+r, col chunks
// [4j+64c..+3].  ax/pg row state in LDS (ax recurrence ax -= step*pg).
// Deltas vs R8: (1) x is register-resident per grad pair (col=t>>1) — s_x
// is init-only; (2) the 25-step n-side line search is split across the pair
// halves (l=0..12 / l=13..24) and merged by the xor-1 step of the AND
// butterfly.  Everything else — grad mapping, s_mask atomics, consensus —
// is identical to the 169 us R8 kernel.
__global__ __launch_bounds__(NTHR, 4)
void lbp_fused(const float* __restrict__ xraw_g,
               const float* __restrict__ A_g,
               const float* __restrict__ b_g,
               const float* __restrict__ lower_g,
               float* __restrict__ out_g,
               unsigned* __restrict__ wsu)
{
    const int p    = blockIdx.x;
    const int t    = threadIdx.x;
    const int lane = t & 63;
    const int wave = t >> 6;          // 0..7
    const int g    = lane >> 4;       // 0..3  row sub-group
    const int j    = lane & 15;       // 0..15 col sub-group
    const int wb   = wave * 16;       // wave's base row

    const float* A = A_g + (size_t)p * (MM * NN);

    __shared__ __align__(16) float s_x[NN];                // init/repair only
    __shared__ __align__(16) float s_grad[NN];
    __shared__ __align__(16) float s_xraw[NN];
    __shared__ __align__(16) float s_lower[NN];
    __shared__ __align__(16) float s_p1g[32][NN];          // per-(wave,g) A^T w partials
    __shared__ float s_ax[MM], s_pg[MM];                   // row state (j==0 writes)
    __shared__ float s_redw[8];
    __shared__ unsigned s_redu[8];
    __shared__ unsigned s_mask;
    __shared__ float s_step, s_t0;

    // ---- load A slice into registers (only HBM read of A in the solve) ----
    float4 a[4][4];
    {
        const float* base = A + (size_t)(wb + 4 * g) * NN + 4 * j;
        #pragma unroll
        for (int r = 0; r < 4; ++r)
            #pragma unroll
            for (int c = 0; c < 4; ++c)
                a[r][c] = *(const float4*)(base + r * NN + 64 * c);
    }

    if (t < NN) { s_xraw[t] = xraw_g[p * NN + t]; s_lower[t] = lower_g[p * NN + t]; }

    float bbr[4];
    #pragma unroll
    for (int r = 0; r < 4; ++r) bbr[r] = b_g[p * MM + wb + 4 * g + r];

    const float stepj0 = ldexpf(1.0f, -j);   // pass-2 ballot step 2^-j for this lane

    if (t == 0) { s_mask = 0xFFFFFFFFu; s_step = 0.0f; }
    __syncthreads();

    // ---- init: row stats (ssq, rowsum, A·lower) from registers ----
    float cer[4], clr[4];
    {
        float ssq[4] = {0.f,0.f,0.f,0.f}, rs[4] = {0.f,0.f,0.f,0.f}, al[4] = {0.f,0.f,0.f,0.f};
        #pragma unroll
        for (int c = 0; c < 4; ++c) {
            const float4 lo4 = ((const float4*)s_lower)[j + 16 * c];
            #pragma unroll
            for (int r = 0; r < 4; ++r) {
                const float4 av = a[r][c];
                ssq[r] += av.x*av.x + av.y*av.y + av.z*av.z + av.w*av.w;
                rs[r]  += av.x + av.y + av.z + av.w;
                al[r]  += av.x*lo4.x + av.y*lo4.y + av.z*lo4.z + av.w*lo4.w;
            }
        }
        float alr[4], rsr[4];
        float rmin = INFINITY;
        #pragma unroll
        for (int r = 0; r < 4; ++r) {
            const float ssqs = red16_add(ssq[r]);
            const float rss  = red16_add(rs[r]);
            const float als  = red16_add(al[r]);
            const float rr = fmaxf(sqrtf(ssqs), 1e-12f);
            clr[r] = 1e-12f * rr;                    // slack clamp (unnormalized)
            cer[r] = bbr[r] - EPS * rr;              // feasibility threshold
            const float adw = rss / rr;
            const float sw  = (bbr[r] - als) / rr;
            const float ratio = (adw > 0.f) ? (sw / fmaxf(adw, 1e-12f)) : INFINITY;
            rmin = fminf(rmin, ratio);
            alr[r] = als; rsr[r] = rss;
        }
        RED64_MIN(rmin);
        if (lane == 0) s_redw[wave] = rmin;
        __syncthreads();
        if (t == 0) {
            float m = s_redw[0];
            #pragma unroll
            for (int w = 1; w < 8; ++w) m = fminf(m, s_redw[w]);
            s_t0 = fmaxf(0.5f * m, 2.0f * EPS);
        }
        __syncthreads();
        const float t0v = s_t0;
        float xi = 0.f;
        if (t < NN) { xi = s_lower[t] + t0v; s_x[t] = xi; }
        float axc0[4];
        #pragma unroll
        for (int r = 0; r < 4; ++r) {
            axc0[r] = alr[r] + t0v * rsr[r];
            if (j == 0) { s_ax[wb + 4 * g + r] = axc0[r]; s_pg[wb + 4 * g + r] = 0.f; }
        }

        // feasibility repair (faithful to module; no-op for these inputs)
        int okf = 1;
        #pragma unroll
        for (int r = 0; r < 4; ++r) okf = okf && (axc0[r] <= cer[r]);
        if (t < NN) okf = okf && (xi >= s_lower[t] + EPS);
        const int feas = __syncthreads_and(okf);
        if (!feas) {
            if (t < NN) s_x[t] = 0.5f * (fmaxf(s_x[t], 0.f) + s_lower[t]);
            __syncthreads();
            float axp[4] = {0.f,0.f,0.f,0.f};
            #pragma unroll
            for (int c = 0; c < 4; ++c) {
                const float4 x4 = ((const float4*)s_x)[j + 16 * c];
                #pragma unroll
                for (int r = 0; r < 4; ++r) {
                    const float4 av = a[r][c];
                    axp[r] += av.x*x4.x + av.y*x4.y + av.z*x4.z + av.w*x4.w;
                }
            }
            #pragma unroll
            for (int r = 0; r < 4; ++r) {
                const float s = red16_add(axp[r]);
                if (j == 0) s_ax[wb + 4 * g + r] = s;     // s_pg stays 0
            }
            __syncthreads();
        }
    }

    // x becomes register-resident for the whole loop: pair (2c,2c+1) both
    // hold col c's x (barrier above orders the init/repair s_x writes).
    float xr = s_x[t >> 1];

    // ------------------------------ main loop ------------------------------
    for (int k = 0; k < K_ITER; ++k) {
        // pass 1: ax recurrence + barrier weights + gbar partials.
        float axm[4];                         // live through pass 2's ballots
        {
            const float stp = s_step;
            float wm[4];
            #pragma unroll
            for (int r = 0; r < 4; ++r) {
                const int m = wb + 4 * g + r;
                axm[r] = s_ax[m] - stp * s_pg[m];
                wm[r]  = MU / fmaxf(bbr[r] - axm[r], clr[r]);
            }
            if (j == 0) {
                #pragma unroll
                for (int r = 0; r < 4; ++r) s_ax[wb + 4 * g + r] = axm[r];
            }
            #pragma unroll
            for (int c = 0; c < 4; ++c) {
                float4 gb;
                gb.x = a[0][c].x*wm[0] + a[1][c].x*wm[1] + a[2][c].x*wm[2] + a[3][c].x*wm[3];
                gb.y = a[0][c].y*wm[0] + a[1][c].y*wm[1] + a[2][c].y*wm[2] + a[3][c].y*wm[3];
                gb.z = a[0][c].z*wm[0] + a[1][c].z*wm[1] + a[2][c].z*wm[2] + a[3][c].z*wm[3];
                gb.w = a[0][c].w*wm[0] + a[1][c].w*wm[1] + a[2][c].w*wm[2] + a[3][c].w*wm[3];
                ((float4*)s_p1g[wave * 4 + g])[j + 16 * c] = gb;
            }
        }
        __syncthreads();                                   // sync1

        // grad + n-side line-search — pair-split (R8 mapping): lanes (2c,2c+1)
        // sum 16 partials each for col c, merge via xor-1 (DPP).  The 25-step
        // search splits across the pair: half0 tests l=0..12, half1 l=13..24
        // (st0 = 2^-13 exact); the AND butterfly's xor-1 step merges ranges.
        {
            const int col  = t >> 1;
            const int half = t & 1;
            float gsum = 0.f;
            #pragma unroll
            for (int q = 0; q < 16; ++q) gsum += s_p1g[half * 16 + q][col];
            gsum += __shfl_xor(gsum, 1);
            const float xt = xr;
            const float gr = (xt - s_xraw[col]) + gsum + MU / fmaxf(xt - s_lower[col], 1e-12f);
            if (half == 0) s_grad[col] = gr;
            unsigned mn = 0u;
            const float loe = s_lower[col] + EPS;
            float st = half ? 0x1p-13f : 1.0f;
            #pragma unroll
            for (int i = 0; i < 13; ++i) {                 // half1's i=12 -> bit 25 (stripped)
                if (xt - st * gr >= loe) mn |= (1u << (half * 13 + i));
                st *= 0.5f;
            }
            mn |= half ? ~0x03FFE000u : ~0x00001FFFu;      // own-range only
            RED64_AND(mn);
            if (lane == 0) atomicAnd(&s_mask, mn);
        }
        __syncthreads();                                   // sync2

        // pass 2: pg = A*grad + fused m-side line-search ballots (vs axm)
        {
            float pg[4] = {0.f,0.f,0.f,0.f};
            #pragma unroll
            for (int c = 0; c < 4; ++c) {
                const float4 g4 = ((const float4*)s_grad)[j + 16 * c];
                #pragma unroll
                for (int r = 0; r < 4; ++r) {
                    const float4 av = a[r][c];
                    pg[r] += av.x*g4.x + av.y*g4.y + av.z*g4.z + av.w*g4.w;
                }
            }
            unsigned mand = 0xFFFFFFFFu;
            #pragma unroll
            for (int r = 0; r < 4; ++r) {
                const float pgs = red16_add(pg[r]);        // all 16 lanes get row sum
                if (j == 0) s_pg[wb + 4 * g + r] = pgs;
                const bool ok0 = (axm[r] - stepj0 * pgs) <= cer[r];              // step j
                const bool ok1 = (axm[r] - (stepj0 * 0x1p-16f) * pgs) <= cer[r]; // step j+16
                const unsigned long long b0 = __ballot(ok0);
                const unsigned long long b1 = __ballot(ok1);
                const unsigned f = ((unsigned)(b0 >> (16 * g)) & 0xFFFFu)
                                 | (((unsigned)(b1 >> (16 * g)) & 0x1FFu) << 16);
                mand &= (f | 0xFE000000u);
            }
            mand &= __shfl_xor(mand, 16);
            mand &= __shfl_xor(mand, 32);
            if (lane == 0) atomicAnd(&s_mask, mand);
        }
        __syncthreads();                                   // sync3 (s_mask final)

        // ---- grid consensus: flag-store + master OR-reduce + broadcast ----
        const unsigned tag = (unsigned)(k + 1) << 25;
        if (p == 0) {
            __builtin_amdgcn_s_setprio(1);                 // master reduce is grid-critical
            unsigned bad;
            if (t == 0) {
                bad = (~s_mask) & FULLMASK;
            } else {
                unsigned v;
                while ((((v = AGLOAD(&wsu[W_FLAG(t)])) >> 25)) != (unsigned)(k + 1))
                    __builtin_amdgcn_s_sleep(1);
                bad = v & FULLMASK;
            }
            RED64_OR(bad);
            if (lane == 0) s_redu[wave] = bad;
            __syncthreads();
            if (t == 0) {
                unsigned orall = 0u;
                #pragma unroll
                for (int w = 0; w < 8; ++w) orall |= s_redu[w];
                const unsigned gm = FULLMASK & ~orall;
                #pragma unroll
                for (int i = 0; i < NBC; ++i)              // bcast ASAP, before sync
                    AGSTORE(&wsu[W_BCAST(i)], tag | gm);
                s_step = gm ? ldexpf(1.0f, -(__ffs(gm) - 1)) : 0.0f;
                s_mask = 0xFFFFFFFFu;                      // re-arm for next iter
            }
            __builtin_amdgcn_s_setprio(0);
            __syncthreads();                               // sync4 (master)
        } else {
            if (t == 0) {
                AGSTORE(&wsu[W_FLAG(p)], tag | ((~s_mask) & FULLMASK));
                s_mask = 0xFFFFFFFFu;                      // re-arm for next iter
                unsigned v;
                while ((((v = AGLOAD(&wsu[W_BCAST(p & (NBC - 1))])) >> 25)) != (unsigned)(k + 1))
                    __builtin_amdgcn_s_sleep(1);
                const unsigned gm = v & FULLMASK;
                s_step = gm ? ldexpf(1.0f, -(__ffs(gm) - 1)) : 0.0f;
            }
            __syncthreads();                               // sync4
        }

        // epilogue: register x update (broadcast read of own col's grad)
        xr -= s_step * s_grad[t >> 1];
        // ordering: s_grad read here (post-sync4) precedes next iter's grad
        // write via sync1; s_ax/s_pg writes (pre-sync3) -> next pass1 reads
        // (post-sync4); s_step written before sync4, consumed here/next pass1.
    }

    if ((t & 1) == 0) out_g[p * NN + (t >> 1)] = fmaxf(xr, 0.0f);
}

// -------------------------------------------------------------- launch ----
extern "C" void kernel_launch(void* const* d_in, const int* in_sizes, int n_in,
                              void* d_out, int out_size, void* d_ws, size_t ws_size,
                              hipStream_t stream) {
    const float* xraw  = (const float*)d_in[0];
    const float* A     = (const float*)d_in[1];
    const float* b     = (const float*)d_in[2];
    const float* lower = (const float*)d_in[3];
    float* out = (float*)d_out;
    unsigned* wsu = (unsigned*)d_ws;

    lbp_ws_init<<<(W_END + 1023) / 1024, 1024, 0, stream>>>(wsu);
    lbp_fused<<<NPROB, NTHR, 0, stream>>>(xraw, A, b, lower, out, wsu);
}

// Round 11
// 249.520 us; speedup vs baseline: 1.0856x; 1.0088x over previous
//
#include <hip/hip_runtime.h>

#define K_ITER   30
#define MU       0.01f
#define EPS      1e-6f
#define MAX_LS   25
#define FULLMASK 0x01FFFFFFu
#define MM       128
#define NN       256
#define NPROB    512
#define NTHR     512          // 8 waves/block; launch_bounds(512,4) -> 2 blocks/CU guaranteed

// ---- ws layout (unsigned words); zero-initialized each launch ----
// flag[p]  : one 128B line per block: ((k+1)<<25) | bad-bits   (written by block p)
// bcast[i] : 16 lines: ((k+1)<<25) | gm                        (written by master t0)
#define LSTRIDE 32
#define NBC     16
#define W_FLAG(p)  ((p)*LSTRIDE)
#define W_BCAST(i) (NPROB*LSTRIDE + (i)*LSTRIDE)
#define W_END      (NPROB*LSTRIDE + NBC*LSTRIDE)   // 16896 words

// --- cross-lane helpers ---------------------------------------------------
#define RED64_AND(v) do { v &= __shfl_xor(v, 1);  v &= __shfl_xor(v, 2);  v &= __shfl_xor(v, 4); \
                          v &= __shfl_xor(v, 8);  v &= __shfl_xor(v, 16); v &= __shfl_xor(v, 32); } while (0)
#define RED64_OR(v)  do { v |= __shfl_xor(v, 1);  v |= __shfl_xor(v, 2);  v |= __shfl_xor(v, 4); \
                          v |= __shfl_xor(v, 8);  v |= __shfl_xor(v, 16); v |= __shfl_xor(v, 32); } while (0)
#define RED64_MIN(v) do { v = fminf(v, __shfl_xor(v, 1));  v = fminf(v, __shfl_xor(v, 2)); \
                          v = fminf(v, __shfl_xor(v, 4));  v = fminf(v, __shfl_xor(v, 8)); \
                          v = fminf(v, __shfl_xor(v, 16)); v = fminf(v, __shfl_xor(v, 32)); } while (0)

#define AGLOAD(p)     __hip_atomic_load((p),      __ATOMIC_RELAXED, __HIP_MEMORY_SCOPE_AGENT)
#define AGSTORE(p, v) __hip_atomic_store((p), (v), __ATOMIC_RELAXED, __HIP_MEMORY_SCOPE_AGENT)

// DPP circular row_ror reduction: sum over each 16-lane group; every lane of
// the group ends with the full 16-sum (VALU pipe only — no DS traffic).
__device__ __forceinline__ float red16_add(float v) {
    v += __int_as_float(__builtin_amdgcn_update_dpp(0, __float_as_int(v), 0x128, 0xF, 0xF, false)); // ror:8
    v += __int_as_float(__builtin_amdgcn_update_dpp(0, __float_as_int(v), 0x124, 0xF, 0xF, false)); // ror:4
    v += __int_as_float(__builtin_amdgcn_update_dpp(0, __float_as_int(v), 0x122, 0xF, 0xF, false)); // ror:2
    v += __int_as_float(__builtin_amdgcn_update_dpp(0, __float_as_int(v), 0x121, 0xF, 0xF, false)); // ror:1
    return v;
}

// -------------------------------------------------------- ws clear ----
__global__ void lbp_ws_init(unsigned* __restrict__ wsu)
{
    const int idx = blockIdx.x * 1024 + threadIdx.x;
    if (idx < W_END) wsu[idx] = 0u;
}

// Persistent kernel (exact R8 structure + fenceless step delivery): block p
// owns problem p; A slice in 64 regs/thread (AGPR half of unified file;
// 64 VGPR + 64 AGPR = exactly the 128-reg budget for 2 blocks/CU — any
// loop-carried register addition spills, measured R9/R10).
// Lane (g=lane>>4, j=lane&15) of wave w holds rows 16w+4g+r, col chunks
// [4j+64c..+3].  ax/pg row state in LDS.
// Consensus: blocks store tag|bad flags; master block OR-reduces and
// publishes tag|gm to 16 bcast lines; EVERY thread polls its block's bcast
// line directly (coalesced one-load-per-wave), computes step locally, and
// runs the epilogue (s_x update; j==0 lanes advance s_ax -= step*s_pg, the
// same fma the R8 pass 1 recurrence used — bit-identical).  This deletes
// s_step and the 4th barrier; 3 __syncthreads/iter for non-master blocks.
__global__ __launch_bounds__(NTHR, 4)
void lbp_fused(const float* __restrict__ xraw_g,
               const float* __restrict__ A_g,
               const float* __restrict__ b_g,
               const float* __restrict__ lower_g,
               float* __restrict__ out_g,
               unsigned* __restrict__ wsu)
{
    const int p    = blockIdx.x;
    const int t    = threadIdx.x;
    const int lane = t & 63;
    const int wave = t >> 6;          // 0..7
    const int g    = lane >> 4;       // 0..3  row sub-group
    const int j    = lane & 15;       // 0..15 col sub-group
    const int wb   = wave * 16;       // wave's base row

    const float* A = A_g + (size_t)p * (MM * NN);

    __shared__ __align__(16) float s_x[NN];
    __shared__ __align__(16) float s_grad[NN];
    __shared__ __align__(16) float s_xraw[NN];
    __shared__ __align__(16) float s_lower[NN];
    __shared__ __align__(16) float s_p1g[32][NN];          // per-(wave,g) A^T w partials
    __shared__ float s_ax[MM], s_pg[MM];                   // row state (j==0 writes)
    __shared__ float s_redw[8];
    __shared__ unsigned s_redu[8];
    __shared__ unsigned s_mask;
    __shared__ float s_t0;

    // ---- load A slice into registers (only HBM read of A in the solve) ----
    float4 a[4][4];
    {
        const float* base = A + (size_t)(wb + 4 * g) * NN + 4 * j;
        #pragma unroll
        for (int r = 0; r < 4; ++r)
            #pragma unroll
            for (int c = 0; c < 4; ++c)
                a[r][c] = *(const float4*)(base + r * NN + 64 * c);
    }

    if (t < NN) { s_xraw[t] = xraw_g[p * NN + t]; s_lower[t] = lower_g[p * NN + t]; }

    float bbr[4];
    #pragma unroll
    for (int r = 0; r < 4; ++r) bbr[r] = b_g[p * MM + wb + 4 * g + r];

    const float stepj0 = ldexpf(1.0f, -j);   // pass-2 ballot step 2^-j for this lane

    if (t == 0) s_mask = 0xFFFFFFFFu;
    __syncthreads();

    // ---- init: row stats (ssq, rowsum, A·lower) from registers ----
    float cer[4], clr[4];
    {
        float ssq[4] = {0.f,0.f,0.f,0.f}, rs[4] = {0.f,0.f,0.f,0.f}, al[4] = {0.f,0.f,0.f,0.f};
        #pragma unroll
        for (int c = 0; c < 4; ++c) {
            const float4 lo4 = ((const float4*)s_lower)[j + 16 * c];
            #pragma unroll
            for (int r = 0; r < 4; ++r) {
                const float4 av = a[r][c];
                ssq[r] += av.x*av.x + av.y*av.y + av.z*av.z + av.w*av.w;
                rs[r]  += av.x + av.y + av.z + av.w;
                al[r]  += av.x*lo4.x + av.y*lo4.y + av.z*lo4.z + av.w*lo4.w;
            }
        }
        float alr[4], rsr[4];
        float rmin = INFINITY;
        #pragma unroll
        for (int r = 0; r < 4; ++r) {
            const float ssqs = red16_add(ssq[r]);
            const float rss  = red16_add(rs[r]);
            const float als  = red16_add(al[r]);
            const float rr = fmaxf(sqrtf(ssqs), 1e-12f);
            clr[r] = 1e-12f * rr;                    // slack clamp (unnormalized)
            cer[r] = bbr[r] - EPS * rr;              // feasibility threshold
            const float adw = rss / rr;
            const float sw  = (bbr[r] - als) / rr;
            const float ratio = (adw > 0.f) ? (sw / fmaxf(adw, 1e-12f)) : INFINITY;
            rmin = fminf(rmin, ratio);
            alr[r] = als; rsr[r] = rss;
        }
        RED64_MIN(rmin);
        if (lane == 0) s_redw[wave] = rmin;
        __syncthreads();
        if (t == 0) {
            float m = s_redw[0];
            #pragma unroll
            for (int w = 1; w < 8; ++w) m = fminf(m, s_redw[w]);
            s_t0 = fmaxf(0.5f * m, 2.0f * EPS);
        }
        __syncthreads();
        const float t0v = s_t0;
        float xi = 0.f;
        if (t < NN) { xi = s_lower[t] + t0v; s_x[t] = xi; }
        float axc0[4];
        #pragma unroll
        for (int r = 0; r < 4; ++r) {
            axc0[r] = alr[r] + t0v * rsr[r];
            if (j == 0) { s_ax[wb + 4 * g + r] = axc0[r]; s_pg[wb + 4 * g + r] = 0.f; }
        }

        // feasibility repair (faithful to module; no-op for these inputs)
        int okf = 1;
        #pragma unroll
        for (int r = 0; r < 4; ++r) okf = okf && (axc0[r] <= cer[r]);
        if (t < NN) okf = okf && (xi >= s_lower[t] + EPS);
        const int feas = __syncthreads_and(okf);
        if (!feas) {
            if (t < NN) s_x[t] = 0.5f * (fmaxf(s_x[t], 0.f) + s_lower[t]);
            __syncthreads();
            float axp[4] = {0.f,0.f,0.f,0.f};
            #pragma unroll
            for (int c = 0; c < 4; ++c) {
                const float4 x4 = ((const float4*)s_x)[j + 16 * c];
                #pragma unroll
                for (int r = 0; r < 4; ++r) {
                    const float4 av = a[r][c];
                    axp[r] += av.x*x4.x + av.y*x4.y + av.z*x4.z + av.w*x4.w;
                }
            }
            #pragma unroll
            for (int r = 0; r < 4; ++r) {
                const float s = red16_add(axp[r]);
                if (j == 0) s_ax[wb + 4 * g + r] = s;     // s_pg stays 0
            }
            __syncthreads();
        }
    }

    // ------------------------------ main loop ------------------------------
    for (int k = 0; k < K_ITER; ++k) {
        // pass 1: barrier weights + gbar partials (s_ax pre-advanced by the
        // previous epilogue; same values the R8 recurrence produced).
        float axm[4];                         // live through pass 2's ballots
        {
            #pragma unroll
            for (int r = 0; r < 4; ++r) axm[r] = s_ax[wb + 4 * g + r];
            float wm[4];
            #pragma unroll
            for (int r = 0; r < 4; ++r) wm[r] = MU / fmaxf(bbr[r] - axm[r], clr[r]);
            #pragma unroll
            for (int c = 0; c < 4; ++c) {
                float4 gb;
                gb.x = a[0][c].x*wm[0] + a[1][c].x*wm[1] + a[2][c].x*wm[2] + a[3][c].x*wm[3];
                gb.y = a[0][c].y*wm[0] + a[1][c].y*wm[1] + a[2][c].y*wm[2] + a[3][c].y*wm[3];
                gb.z = a[0][c].z*wm[0] + a[1][c].z*wm[1] + a[2][c].z*wm[2] + a[3][c].z*wm[3];
                gb.w = a[0][c].w*wm[0] + a[1][c].w*wm[1] + a[2][c].w*wm[2] + a[3][c].w*wm[3];
                ((float4*)s_p1g[wave * 4 + g])[j + 16 * c] = gb;
            }
        }
        __syncthreads();                                   // sync1

        // grad + n-side line-search — pair-split (R8 mapping): lanes (2c,2c+1)
        // sum 16 partials each for col c, merge via xor-1 (DPP quad-perm).
        {
            const int col  = t >> 1;
            const int half = t & 1;
            float gsum = 0.f;
            #pragma unroll
            for (int q = 0; q < 16; ++q) gsum += s_p1g[half * 16 + q][col];
            gsum += __shfl_xor(gsum, 1);
            const float xt = s_x[col];
            const float gr = (xt - s_xraw[col]) + gsum + MU / fmaxf(xt - s_lower[col], 1e-12f);
            if (half == 0) s_grad[col] = gr;
            unsigned mn = 0u;
            const float loe = s_lower[col] + EPS;
            float st = 1.0f;
            #pragma unroll
            for (int l = 0; l < MAX_LS; ++l) {
                if (xt - st * gr >= loe) mn |= (1u << l);
                st *= 0.5f;
            }
            RED64_AND(mn);
            if (lane == 0) atomicAnd(&s_mask, mn);
        }
        __syncthreads();                                   // sync2

        // pass 2: pg = A*grad + fused m-side line-search ballots (vs axm)
        {
            float pg[4] = {0.f,0.f,0.f,0.f};
            #pragma unroll
            for (int c = 0; c < 4; ++c) {
                const float4 g4 = ((const float4*)s_grad)[j + 16 * c];
                #pragma unroll
                for (int r = 0; r < 4; ++r) {
                    const float4 av = a[r][c];
                    pg[r] += av.x*g4.x + av.y*g4.y + av.z*g4.z + av.w*g4.w;
                }
            }
            unsigned mand = 0xFFFFFFFFu;
            #pragma unroll
            for (int r = 0; r < 4; ++r) {
                const float pgs = red16_add(pg[r]);        // all 16 lanes get row sum
                if (j == 0) s_pg[wb + 4 * g + r] = pgs;
                const bool ok0 = (axm[r] - stepj0 * pgs) <= cer[r];              // step j
                const bool ok1 = (axm[r] - (stepj0 * 0x1p-16f) * pgs) <= cer[r]; // step j+16
                const unsigned long long b0 = __ballot(ok0);
                const unsigned long long b1 = __ballot(ok1);
                const unsigned f = ((unsigned)(b0 >> (16 * g)) & 0xFFFFu)
                                 | (((unsigned)(b1 >> (16 * g)) & 0x1FFu) << 16);
                mand &= (f | 0xFE000000u);
            }
            mand &= __shfl_xor(mand, 16);
            mand &= __shfl_xor(mand, 32);
            if (lane == 0) atomicAnd(&s_mask, mand);
        }
        __syncthreads();                                   // sync3 (s_mask final)

        // ---- grid consensus: flag-store + master OR-reduce + broadcast.
        // Every thread polls its bcast line directly (one coalesced load per
        // wave); no s_step, no 4th barrier.
        const unsigned tag = (unsigned)(k + 1) << 25;
        if (p == 0) {
            __builtin_amdgcn_s_setprio(1);                 // master reduce is grid-critical
            unsigned bad;
            if (t == 0) {
                bad = (~s_mask) & FULLMASK;
            } else {
                unsigned v;
                while ((((v = AGLOAD(&wsu[W_FLAG(t)])) >> 25)) != (unsigned)(k + 1))
                    __builtin_amdgcn_s_sleep(1);
                bad = v & FULLMASK;
            }
            RED64_OR(bad);
            if (lane == 0) s_redu[wave] = bad;
            __syncthreads();                               // master-internal barrier
            if (t == 0) {
                unsigned orall = 0u;
                #pragma unroll
                for (int w = 0; w < 8; ++w) orall |= s_redu[w];
                const unsigned gm = FULLMASK & ~orall;
                #pragma unroll
                for (int i = 0; i < NBC; ++i)
                    AGSTORE(&wsu[W_BCAST(i)], tag | gm);
                s_mask = 0xFFFFFFFFu;                      // re-arm (ordered by next sync1)
            }
            __builtin_amdgcn_s_setprio(0);
        } else {
            if (t == 0) {
                AGSTORE(&wsu[W_FLAG(p)], tag | ((~s_mask) & FULLMASK));
                s_mask = 0xFFFFFFFFu;                      // re-arm (ordered by next sync1)
            }
        }
        unsigned v;
        while ((((v = AGLOAD(&wsu[W_BCAST(p & (NBC - 1))])) >> 25)) != (unsigned)(k + 1))
            __builtin_amdgcn_s_sleep(1);
        const unsigned gm = v & FULLMASK;
        const float step = gm ? ldexpf(1.0f, -(__ffs(gm) - 1)) : 0.0f;

        // epilogue (per-thread, no barrier): x update + row-state advance.
        if (t < NN) s_x[t] -= step * s_grad[t];
        if (j == 0) {
            #pragma unroll
            for (int r = 0; r < 4; ++r) {
                const int m = wb + 4 * g + r;
                s_ax[m] = s_ax[m] - step * s_pg[m];        // same fma as R8's recurrence
            }
        }
        // ordering: s_x/s_ax epilogue writes -> next sync1 -> grad reads;
        // wave w exclusively owns s_ax rows [wb,wb+16) (wave-internal order);
        // s_grad read here was written pre-sync2 of this iteration.
    }

    if (t < NN) out_g[p * NN + t] = fmaxf(s_x[t], 0.0f);
}

// -------------------------------------------------------------- launch ----
extern "C" void kernel_launch(void* const* d_in, const int* in_sizes, int n_in,
                              void* d_out, int out_size, void* d_ws, size_t ws_size,
                              hipStream_t stream) {
    const float* xraw  = (const float*)d_in[0];
    const float* A     = (const float*)d_in[1];
    const float* b     = (const float*)d_in[2];
    const float* lower = (const float*)d_in[3];
    float* out = (float*)d_out;
    unsigned* wsu = (unsigned*)d_ws;

    lbp_ws_init<<<(W_END + 1023) / 1024, 1024, 0, stream>>>(wsu);
    lbp_fused<<<NPROB, NTHR, 0, stream>>>(xraw, A, b, lower, out, wsu);
}

// Round 12
// 243.831 us; speedup vs baseline: 1.1109x; 1.0233x over previous
//
#include <hip/hip_runtime.h>

#define K_ITER   30
#define MU       0.01f
#define EPS      1e-6f
#define MAX_LS   25
#define FULLMASK 0x01FFFFFFu
#define MM       128
#define NN       256
#define NPROB    512
#define NTHR     512          // 8 waves/block; launch_bounds(512,4) -> 2 blocks/CU guaranteed

// ---- ws layout (unsigned words); zero-initialized each launch ----
// flag[p]  : one 128B line per block: ((k+1)<<25) | bad-bits   (written by block p)
// bcast[i] : 16 lines: ((k+1)<<25) | gm                        (written by master t0)
#define LSTRIDE 32
#define NBC     16
#define W_FLAG(p)  ((p)*LSTRIDE)
#define W_BCAST(i) (NPROB*LSTRIDE + (i)*LSTRIDE)
#define W_END      (NPROB*LSTRIDE + NBC*LSTRIDE)   // 16896 words

// --- cross-lane helpers ---------------------------------------------------
#define RED64_AND(v) do { v &= __shfl_xor(v, 1);  v &= __shfl_xor(v, 2);  v &= __shfl_xor(v, 4); \
                          v &= __shfl_xor(v, 8);  v &= __shfl_xor(v, 16); v &= __shfl_xor(v, 32); } while (0)
#define RED64_OR(v)  do { v |= __shfl_xor(v, 1);  v |= __shfl_xor(v, 2);  v |= __shfl_xor(v, 4); \
                          v |= __shfl_xor(v, 8);  v |= __shfl_xor(v, 16); v |= __shfl_xor(v, 32); } while (0)
#define RED64_MIN(v) do { v = fminf(v, __shfl_xor(v, 1));  v = fminf(v, __shfl_xor(v, 2)); \
                          v = fminf(v, __shfl_xor(v, 4));  v = fminf(v, __shfl_xor(v, 8)); \
                          v = fminf(v, __shfl_xor(v, 16)); v = fminf(v, __shfl_xor(v, 32)); } while (0)

#define AGLOAD(p)     __hip_atomic_load((p),      __ATOMIC_RELAXED, __HIP_MEMORY_SCOPE_AGENT)
#define AGSTORE(p, v) __hip_atomic_store((p), (v), __ATOMIC_RELAXED, __HIP_MEMORY_SCOPE_AGENT)

// DPP circular row_ror reduction: sum over each 16-lane group; every lane of
// the group ends with the full 16-sum (VALU pipe only — no DS traffic).
__device__ __forceinline__ float red16_add(float v) {
    v += __int_as_float(__builtin_amdgcn_update_dpp(0, __float_as_int(v), 0x128, 0xF, 0xF, false)); // ror:8
    v += __int_as_float(__builtin_amdgcn_update_dpp(0, __float_as_int(v), 0x124, 0xF, 0xF, false)); // ror:4
    v += __int_as_float(__builtin_amdgcn_update_dpp(0, __float_as_int(v), 0x122, 0xF, 0xF, false)); // ror:2
    v += __int_as_float(__builtin_amdgcn_update_dpp(0, __float_as_int(v), 0x121, 0xF, 0xF, false)); // ror:1
    return v;
}

// -------------------------------------------------------- ws clear ----
__global__ void lbp_ws_init(unsigned* __restrict__ wsu)
{
    const int idx = blockIdx.x * 1024 + threadIdx.x;
    if (idx < W_END) wsu[idx] = 0u;
}

// Persistent kernel (R8 — empirically optimal): block p owns problem p; A
// slice in 64 regs/thread (AGPR half of unified file; 64 VGPR + 64 AGPR =
// exactly the 128-reg budget for 2 blocks/CU.  Measured boundary: ANY
// loop-carried register addition spills — R9/R10/R11 all regressed).
// Lane (g=lane>>4, j=lane&15) of wave w holds rows 16w+4g+r, col chunks
// [4j+64c..+3].  ax/pg row state in LDS; ax recurrence ax -= step*pg (no
// fresh A*x in the loop; pass 2 is pg-only).  Grad phase pair-split
// (col=t>>1; the 2-way LDS bank alias is measured-benign).  Consensus:
// flag-store + master OR-reduce + 16-line broadcast, t0-only polling.
__global__ __launch_bounds__(NTHR, 4)
void lbp_fused(const float* __restrict__ xraw_g,
               const float* __restrict__ A_g,
               const float* __restrict__ b_g,
               const float* __restrict__ lower_g,
               float* __restrict__ out_g,
               unsigned* __restrict__ wsu)
{
    const int p    = blockIdx.x;
    const int t    = threadIdx.x;
    const int lane = t & 63;
    const int wave = t >> 6;          // 0..7
    const int g    = lane >> 4;       // 0..3  row sub-group
    const int j    = lane & 15;       // 0..15 col sub-group
    const int wb   = wave * 16;       // wave's base row

    const float* A = A_g + (size_t)p * (MM * NN);

    __shared__ __align__(16) float s_x[NN];
    __shared__ __align__(16) float s_grad[NN];
    __shared__ __align__(16) float s_xraw[NN];
    __shared__ __align__(16) float s_lower[NN];
    __shared__ __align__(16) float s_p1g[32][NN];          // per-(wave,g) A^T w partials
    __shared__ float s_ax[MM], s_pg[MM];                   // row state (j==0 writes)
    __shared__ float s_redw[8];
    __shared__ unsigned s_redu[8];
    __shared__ unsigned s_mask;
    __shared__ float s_step, s_t0;

    // ---- load A slice into registers (only HBM read of A in the solve) ----
    float4 a[4][4];
    {
        const float* base = A + (size_t)(wb + 4 * g) * NN + 4 * j;
        #pragma unroll
        for (int r = 0; r < 4; ++r)
            #pragma unroll
            for (int c = 0; c < 4; ++c)
                a[r][c] = *(const float4*)(base + r * NN + 64 * c);
    }

    if (t < NN) { s_xraw[t] = xraw_g[p * NN + t]; s_lower[t] = lower_g[p * NN + t]; }

    float bbr[4];
    #pragma unroll
    for (int r = 0; r < 4; ++r) bbr[r] = b_g[p * MM + wb + 4 * g + r];

    const float stepj0 = ldexpf(1.0f, -j);   // pass-2 ballot step 2^-j for this lane

    if (t == 0) { s_mask = 0xFFFFFFFFu; s_step = 0.0f; }
    __syncthreads();

    // ---- init: row stats (ssq, rowsum, A·lower) from registers ----
    float cer[4], clr[4];
    {
        float ssq[4] = {0.f,0.f,0.f,0.f}, rs[4] = {0.f,0.f,0.f,0.f}, al[4] = {0.f,0.f,0.f,0.f};
        #pragma unroll
        for (int c = 0; c < 4; ++c) {
            const float4 lo4 = ((const float4*)s_lower)[j + 16 * c];
            #pragma unroll
            for (int r = 0; r < 4; ++r) {
                const float4 av = a[r][c];
                ssq[r] += av.x*av.x + av.y*av.y + av.z*av.z + av.w*av.w;
                rs[r]  += av.x + av.y + av.z + av.w;
                al[r]  += av.x*lo4.x + av.y*lo4.y + av.z*lo4.z + av.w*lo4.w;
            }
        }
        float alr[4], rsr[4];
        float rmin = INFINITY;
        #pragma unroll
        for (int r = 0; r < 4; ++r) {
            const float ssqs = red16_add(ssq[r]);
            const float rss  = red16_add(rs[r]);
            const float als  = red16_add(al[r]);
            const float rr = fmaxf(sqrtf(ssqs), 1e-12f);
            clr[r] = 1e-12f * rr;                    // slack clamp (unnormalized)
            cer[r] = bbr[r] - EPS * rr;              // feasibility threshold
            const float adw = rss / rr;
            const float sw  = (bbr[r] - als) / rr;
            const float ratio = (adw > 0.f) ? (sw / fmaxf(adw, 1e-12f)) : INFINITY;
            rmin = fminf(rmin, ratio);
            alr[r] = als; rsr[r] = rss;
        }
        RED64_MIN(rmin);
        if (lane == 0) s_redw[wave] = rmin;
        __syncthreads();
        if (t == 0) {
            float m = s_redw[0];
            #pragma unroll
            for (int w = 1; w < 8; ++w) m = fminf(m, s_redw[w]);
            s_t0 = fmaxf(0.5f * m, 2.0f * EPS);
        }
        __syncthreads();
        const float t0v = s_t0;
        float xi = 0.f;
        if (t < NN) { xi = s_lower[t] + t0v; s_x[t] = xi; }
        float axc0[4];
        #pragma unroll
        for (int r = 0; r < 4; ++r) {
            axc0[r] = alr[r] + t0v * rsr[r];
            if (j == 0) { s_ax[wb + 4 * g + r] = axc0[r]; s_pg[wb + 4 * g + r] = 0.f; }
        }

        // feasibility repair (faithful to module; no-op for these inputs)
        int okf = 1;
        #pragma unroll
        for (int r = 0; r < 4; ++r) okf = okf && (axc0[r] <= cer[r]);
        if (t < NN) okf = okf && (xi >= s_lower[t] + EPS);
        const int feas = __syncthreads_and(okf);
        if (!feas) {
            if (t < NN) s_x[t] = 0.5f * (fmaxf(s_x[t], 0.f) + s_lower[t]);
            __syncthreads();
            float axp[4] = {0.f,0.f,0.f,0.f};
            #pragma unroll
            for (int c = 0; c < 4; ++c) {
                const float4 x4 = ((const float4*)s_x)[j + 16 * c];
                #pragma unroll
                for (int r = 0; r < 4; ++r) {
                    const float4 av = a[r][c];
                    axp[r] += av.x*x4.x + av.y*x4.y + av.z*x4.z + av.w*x4.w;
                }
            }
            #pragma unroll
            for (int r = 0; r < 4; ++r) {
                const float s = red16_add(axp[r]);
                if (j == 0) s_ax[wb + 4 * g + r] = s;     // s_pg stays 0
            }
            __syncthreads();
        }
    }

    // ------------------------------ main loop ------------------------------
    for (int k = 0; k < K_ITER; ++k) {
        // pass 1: ax recurrence + barrier weights + gbar partials.
        float axm[4];                         // live through pass 2's ballots
        {
            const float stp = s_step;
            float wm[4];
            #pragma unroll
            for (int r = 0; r < 4; ++r) {
                const int m = wb + 4 * g + r;
                axm[r] = s_ax[m] - stp * s_pg[m];
                wm[r]  = MU / fmaxf(bbr[r] - axm[r], clr[r]);
            }
            if (j == 0) {
                #pragma unroll
                for (int r = 0; r < 4; ++r) s_ax[wb + 4 * g + r] = axm[r];
            }
            #pragma unroll
            for (int c = 0; c < 4; ++c) {
                float4 gb;
                gb.x = a[0][c].x*wm[0] + a[1][c].x*wm[1] + a[2][c].x*wm[2] + a[3][c].x*wm[3];
                gb.y = a[0][c].y*wm[0] + a[1][c].y*wm[1] + a[2][c].y*wm[2] + a[3][c].y*wm[3];
                gb.z = a[0][c].z*wm[0] + a[1][c].z*wm[1] + a[2][c].z*wm[2] + a[3][c].z*wm[3];
                gb.w = a[0][c].w*wm[0] + a[1][c].w*wm[1] + a[2][c].w*wm[2] + a[3][c].w*wm[3];
                ((float4*)s_p1g[wave * 4 + g])[j + 16 * c] = gb;
            }
        }
        __syncthreads();                                   // sync1

        // grad + n-side line-search mask — pair-split across all 8 waves:
        // lanes (2c,2c+1) of the block each sum 16 partials for col c.
        {
            const int col  = t >> 1;
            const int half = t & 1;
            float gsum = 0.f;
            #pragma unroll
            for (int q = 0; q < 16; ++q) gsum += s_p1g[half * 16 + q][col];
            gsum += __shfl_xor(gsum, 1);
            const float xt = s_x[col];
            const float gr = (xt - s_xraw[col]) + gsum + MU / fmaxf(xt - s_lower[col], 1e-12f);
            if (half == 0) s_grad[col] = gr;
            unsigned mn = 0u;
            const float loe = s_lower[col] + EPS;
            float st = 1.0f;
            #pragma unroll
            for (int l = 0; l < MAX_LS; ++l) {
                if (xt - st * gr >= loe) mn |= (1u << l);
                st *= 0.5f;
            }
            RED64_AND(mn);
            if (lane == 0) atomicAnd(&s_mask, mn);
        }
        __syncthreads();                                   // sync2

        // pass 2: pg = A*grad + fused m-side line-search ballots (vs axm)
        {
            float pg[4] = {0.f,0.f,0.f,0.f};
            #pragma unroll
            for (int c = 0; c < 4; ++c) {
                const float4 g4 = ((const float4*)s_grad)[j + 16 * c];
                #pragma unroll
                for (int r = 0; r < 4; ++r) {
                    const float4 av = a[r][c];
                    pg[r] += av.x*g4.x + av.y*g4.y + av.z*g4.z + av.w*g4.w;
                }
            }
            unsigned mand = 0xFFFFFFFFu;
            #pragma unroll
            for (int r = 0; r < 4; ++r) {
                const float pgs = red16_add(pg[r]);        // all 16 lanes get row sum
                if (j == 0) s_pg[wb + 4 * g + r] = pgs;
                const bool ok0 = (axm[r] - stepj0 * pgs) <= cer[r];              // step j
                const bool ok1 = (axm[r] - (stepj0 * 0x1p-16f) * pgs) <= cer[r]; // step j+16
                const unsigned long long b0 = __ballot(ok0);
                const unsigned long long b1 = __ballot(ok1);
                const unsigned f = ((unsigned)(b0 >> (16 * g)) & 0xFFFFu)
                                 | (((unsigned)(b1 >> (16 * g)) & 0x1FFu) << 16);
                mand &= (f | 0xFE000000u);
            }
            mand &= __shfl_xor(mand, 16);
            mand &= __shfl_xor(mand, 32);
            if (lane == 0) atomicAnd(&s_mask, mand);
        }
        __syncthreads();                                   // sync3 (s_mask final)

        // ---- grid consensus: flag-store + master OR-reduce + broadcast ----
        const unsigned tag = (unsigned)(k + 1) << 25;
        if (p == 0) {
            __builtin_amdgcn_s_setprio(1);                 // master reduce is grid-critical
            unsigned bad;
            if (t == 0) {
                bad = (~s_mask) & FULLMASK;
            } else {
                unsigned v;
                while ((((v = AGLOAD(&wsu[W_FLAG(t)])) >> 25)) != (unsigned)(k + 1))
                    __builtin_amdgcn_s_sleep(1);
                bad = v & FULLMASK;
            }
            RED64_OR(bad);
            if (lane == 0) s_redu[wave] = bad;
            __syncthreads();
            if (t == 0) {
                unsigned orall = 0u;
                #pragma unroll
                for (int w = 0; w < 8; ++w) orall |= s_redu[w];
                const unsigned gm = FULLMASK & ~orall;
                #pragma unroll
                for (int i = 0; i < NBC; ++i)              // bcast ASAP, before sync
                    AGSTORE(&wsu[W_BCAST(i)], tag | gm);
                s_step = gm ? ldexpf(1.0f, -(__ffs(gm) - 1)) : 0.0f;
                s_mask = 0xFFFFFFFFu;                      // re-arm for next iter
            }
            __builtin_amdgcn_s_setprio(0);
            __syncthreads();                               // sync4 (master)
        } else {
            if (t == 0) {
                AGSTORE(&wsu[W_FLAG(p)], tag | ((~s_mask) & FULLMASK));
                s_mask = 0xFFFFFFFFu;                      // re-arm for next iter
                unsigned v;
                while ((((v = AGLOAD(&wsu[W_BCAST(p & (NBC - 1))])) >> 25)) != (unsigned)(k + 1))
                    __builtin_amdgcn_s_sleep(1);
                const unsigned gm = v & FULLMASK;
                s_step = gm ? ldexpf(1.0f, -(__ffs(gm) - 1)) : 0.0f;
            }
            __syncthreads();                               // sync4
        }

        // epilogue: x update only (ax advanced by next pass 1's recurrence)
        if (t < NN) s_x[t] -= s_step * s_grad[t];
        // ordering: s_x writes -> next sync1 -> grad reads; s_ax/s_pg writes
        // (pass1/pass2, before sync3) -> next pass1 reads (after sync4);
        // s_step written before sync4, consumed here and at next pass1 top.
    }

    if (t < NN) out_g[p * NN + t] = fmaxf(s_x[t], 0.0f);
}

// -------------------------------------------------------------- launch ----
extern "C" void kernel_launch(void* const* d_in, const int* in_sizes, int n_in,
                              void* d_out, int out_size, void* d_ws, size_t ws_size,
                              hipStream_t stream) {
    const float* xraw  = (const float*)d_in[0];
    const float* A     = (const float*)d_in[1];
    const float* b     = (const float*)d_in[2];
    const float* lower = (const float*)d_in[3];
    float* out = (float*)d_out;
    unsigned* wsu = (unsigned*)d_ws;

    lbp_ws_init<<<(W_END + 1023) / 1024, 1024, 0, stream>>>(wsu);
    lbp_fused<<<NPROB, NTHR, 0, stream>>>(xraw, A, b, lower, out, wsu);
}